// Round 7
// baseline (1448.354 us; speedup 1.0000x reference)
//
#include <hip/hip_runtime.h>
#include <hip/hip_bf16.h>
#include <math.h>

typedef __attribute__((ext_vector_type(8))) short short8;
typedef __attribute__((ext_vector_type(4))) float f32x4;

#define MFMA16(a, b, c) __builtin_amdgcn_mfma_f32_16x16x32_bf16((a), (b), (c), 0, 0, 0)

#define BB 256
#define TT 64
#define VOCAB 10000
#define WORD 512
#define RNN 512
#define NC 2560          /* 2048 gates + 512 sentinel-gate pre */
#define NV 10001
#define NVP 10016
#define NTILES 626       /* NVP/16 */

__device__ __forceinline__ float sigf(float x) { return 1.f / (1.f + __expf(-x)); }
__device__ __forceinline__ float bf2f(short s) {
    union { unsigned int u; float f; } v;
    v.u = ((unsigned int)(unsigned short)s) << 16;
    return v.f;
}
__device__ __forceinline__ short f2bfs(float x) {
    __hip_bfloat16 h = __float2bfloat16(x);
    return *reinterpret_cast<short*>(&h);
}

// async global->LDS, 16B per lane. lds dest = wave-uniform base + lane*16 (HW rule).
__device__ __forceinline__ void gload_lds16(const void* g, void* l) {
    __builtin_amdgcn_global_load_lds((const __attribute__((address_space(1))) void*)g,
                                     (__attribute__((address_space(3))) void*)l, 16, 0, 0);
}

// stage one 16KB fragment-order tile: 4 waves x 4KB each
__device__ __forceinline__ void stage_tile(const short8* gsrc, void* lbuf, int w, int lane) {
    const char* g = (const char*)gsrc + w * 4096 + lane * 16;
    char* l = (char*)lbuf + w * 4096;
#pragma unroll
    for (int i = 0; i < 4; i++) gload_lds16(g + i * 1024, l + i * 1024);
}

// ---------------- prep: ONE segmented transpose kernel ----------------
// dst[n][k] = bf16(src[k][n]); zero-fill n in [N,dstN). 7 segments, 1D grid of 32x32 tiles.
__global__ void prep_tr(const float* __restrict__ W_ih, const float* __restrict__ W_hh,
                        const float* __restrict__ w2g, const float* __restrict__ h2g,
                        const float* __restrict__ vis2g, const float* __restrict__ oW,
                        __hip_bfloat16* __restrict__ WcatW, __hip_bfloat16* __restrict__ WcatH,
                        __hip_bfloat16* __restrict__ visWt, __hip_bfloat16* __restrict__ outWt) {
    __shared__ float tile[32][33];
    int b = blockIdx.x;
    const float* src; __hip_bfloat16* dst;
    int K, N, ld, dld, dstN, tx, base;
    if (b < 1024)      { base = 0;    tx = 64;  src = W_ih + (size_t)1024 * 2048; K = 512;  N = 2048;  ld = 2048;  dst = WcatW;                        dld = 512;  dstN = 2048; }
    else if (b < 1280) { base = 1024; tx = 16;  src = w2g;   K = 512;  N = 512;   ld = 512;   dst = WcatW + (size_t)2048 * 512;  dld = 512;  dstN = 512; }
    else if (b < 2304) { base = 1280; tx = 64;  src = W_hh;  K = 512;  N = 2048;  ld = 2048;  dst = WcatH;                        dld = 512;  dstN = 2048; }
    else if (b < 2560) { base = 2304; tx = 16;  src = h2g;   K = 512;  N = 512;   ld = 512;   dst = WcatH + (size_t)2048 * 512;  dld = 512;  dstN = 512; }
    else if (b < 4608) { base = 2560; tx = 64;  src = W_ih;  K = 1024; N = 2048;  ld = 2048;  dst = visWt;                        dld = 1024; dstN = 2048; }
    else if (b < 5120) { base = 4608; tx = 16;  src = vis2g; K = 1024; N = 512;   ld = 512;   dst = visWt + (size_t)2048 * 1024; dld = 1024; dstN = 512; }
    else               { base = 5120; tx = 313; src = oW;    K = 512;  N = NV;    ld = NV;    dst = outWt;                        dld = 512;  dstN = NVP; }
    int local = b - base;
    int n0 = (local % tx) * 32, k0 = (local / tx) * 32;
    int txi = threadIdx.x, ty = threadIdx.y;   // 32 x 8
#pragma unroll
    for (int i = 0; i < 32; i += 8) {
        int k = k0 + ty + i, n = n0 + txi;
        tile[ty + i][txi] = (k < K && n < N) ? src[(size_t)k * ld + n] : 0.f;
    }
    __syncthreads();
#pragma unroll
    for (int i = 0; i < 32; i += 8) {
        int n = n0 + ty + i, k = k0 + txi;
        if (n < dstN && k < K) dst[(size_t)n * dld + k] = __float2bfloat16(tile[txi][ty + i]);
    }
}

// ONE segmented fragment-order swizzle: dst[ct][kt][lane] = src[(ct*16+(l&15))][kt*4+(l>>4)]
__global__ void swz_all(const short8* __restrict__ outWt8, const short8* __restrict__ WcatW8,
                        const short8* __restrict__ WcatH8, short8* __restrict__ outSw,
                        short8* __restrict__ preBsw, short8* __restrict__ WHsw) {
    int t = blockIdx.x * 256 + threadIdx.x;
    const short8* src; short8* dst; int local;
    if (t < 626 * 1024)      { src = outWt8; dst = outSw;  local = t; }
    else if (t < 786 * 1024) { src = WcatW8; dst = preBsw; local = t - 626 * 1024; }
    else if (t < 946 * 1024) { src = WcatH8; dst = WHsw;   local = t - 786 * 1024; }
    else return;
    int ct = local >> 10, r = local & 1023, kt = r >> 6, l = r & 63;
    int li = l & 15, q = l >> 4;
    dst[local] = src[(size_t)(ct * 16 + li) * 64 + kt * 4 + q];
}

// zero c/h + cvt vis, one launch
__global__ void init_misc(float* c, __hip_bfloat16* h, const float* __restrict__ vis,
                          __hip_bfloat16* __restrict__ visB) {
    int idx = blockIdx.x * 256 + threadIdx.x;
    if (blockIdx.x < 512) { c[idx] = 0.f; h[idx] = __float2bfloat16(0.f); }
    else { int j = idx - 131072; visB[j] = __float2bfloat16(vis[j]); }
}

// ---------------- big GEMMs ----------------

// visC[256][2560] = vis_bf16 @ visW + bias
__global__ __launch_bounds__(256) void gemm_vis(const __hip_bfloat16* __restrict__ A,
                                                const __hip_bfloat16* __restrict__ Bt,
                                                const float* __restrict__ b_lstm,
                                                const float* __restrict__ vis2g_b,
                                                float* __restrict__ C) {
    int wid = blockIdx.x * 4 + (threadIdx.x >> 6);   // 2560 waves: 16 x 160 tiles
    int mt = wid / 160, nt = wid % 160;
    int lane = threadIdx.x & 63, li = lane & 15, q = lane >> 4;
    const short8* Ap = (const short8*)A + (mt * 16 + li) * 128 + q;   // ld 1024
    const short8* Bp = (const short8*)Bt + (nt * 16 + li) * 128 + q;
    f32x4 acc = {0.f, 0.f, 0.f, 0.f};
#pragma unroll
    for (int kk = 0; kk < 128; kk += 4) acc = MFMA16(Ap[kk], Bp[kk], acc);
    int col = nt * 16 + li;
    float bias = (col < 2048) ? b_lstm[col] : vis2g_b[col - 2048];
#pragma unroll
    for (int r = 0; r < 4; r++) {
        int row = mt * 16 + q * 4 + r;
        C[row * NC + col] = acc[r] + bias;
    }
}

// pre[t*256+b][2560] = emb[word(t,b)] @ WcatW + visC[b]   (bf16 out)
__global__ __launch_bounds__(256) void pre_gemm(const int* __restrict__ seqz,
                                                const float* __restrict__ emb,
                                                const short8* __restrict__ Bsw,
                                                const float* __restrict__ visC,
                                                __hip_bfloat16* __restrict__ pre) {
    __shared__ short8 lds[2][1024];
    int w = threadIdx.x >> 6, lane = threadIdx.x & 63, li = lane & 15, q = lane >> 4;
    int r0 = blockIdx.x * 128 + w * 32;

    short8 a0[16], a1[16];
    {
        int row = r0 + li;
        int t = row >> 8, b = row & 255;
        int wid_ = (t == 0) ? (VOCAB + 1) : seqz[b * TT + (t - 1)];
        const float* er = emb + (size_t)wid_ * WORD + q * 8;
#pragma unroll
        for (int kt = 0; kt < 16; kt++) {
            float4 f0 = ((const float4*)(er + kt * 32))[0];
            float4 f1 = ((const float4*)(er + kt * 32))[1];
            short8 v; v[0]=f2bfs(f0.x); v[1]=f2bfs(f0.y); v[2]=f2bfs(f0.z); v[3]=f2bfs(f0.w);
            v[4]=f2bfs(f1.x); v[5]=f2bfs(f1.y); v[6]=f2bfs(f1.z); v[7]=f2bfs(f1.w);
            a0[kt] = v;
        }
        row = r0 + 16 + li; t = row >> 8; b = row & 255;
        wid_ = (t == 0) ? (VOCAB + 1) : seqz[b * TT + (t - 1)];
        er = emb + (size_t)wid_ * WORD + q * 8;
#pragma unroll
        for (int kt = 0; kt < 16; kt++) {
            float4 f0 = ((const float4*)(er + kt * 32))[0];
            float4 f1 = ((const float4*)(er + kt * 32))[1];
            short8 v; v[0]=f2bfs(f0.x); v[1]=f2bfs(f0.y); v[2]=f2bfs(f0.z); v[3]=f2bfs(f0.w);
            v[4]=f2bfs(f1.x); v[5]=f2bfs(f1.y); v[6]=f2bfs(f1.z); v[7]=f2bfs(f1.w);
            a1[kt] = v;
        }
    }

    int t0 = blockIdx.y * 20, t1 = t0 + 20;   // 8 chunks x 20 = 160
    stage_tile(Bsw + (size_t)t0 * 1024, lds[0], w, lane);
    int ib = 0;
    for (int ct = t0; ct < t1; ++ct, ib ^= 1) {
        __syncthreads();
        if (ct + 1 < t1) stage_tile(Bsw + (size_t)(ct + 1) * 1024, lds[ib ^ 1], w, lane);
        const short8* B = lds[ib];
        f32x4 c0 = {0.f,0.f,0.f,0.f}, c1 = {0.f,0.f,0.f,0.f};
#pragma unroll
        for (int kt = 0; kt < 16; kt++) {
            short8 bv = B[kt * 64 + lane];
            c0 = MFMA16(a0[kt], bv, c0);
            c1 = MFMA16(a1[kt], bv, c1);
        }
        int col = ct * 16 + li;
#pragma unroll
        for (int r = 0; r < 4; r++) {
            int row0 = r0 + q * 4 + r, row1 = row0 + 16;
            pre[(size_t)row0 * NC + col] = __float2bfloat16(c0[r] + visC[(row0 & 255) * NC + col]);
            pre[(size_t)row1 * NC + col] = __float2bfloat16(c1[r] + visC[(row1 & 255) * NC + col]);
        }
    }
}

// ---------------- lse partial (device fn, shared by step launch + tail) ----------------
// lb in [0,128): rg = lb&1 (2 x 128 rows), ch = lb>>1 (64 chunks of 10 tiles).
__device__ __forceinline__ void lse_dev(int lb, const short8* __restrict__ Sprev,
                                        const short8* __restrict__ Bsw,
                                        const float* __restrict__ ob,
                                        float* __restrict__ sume_t,
                                        short8 (*lds)[1024]) {
    int w = threadIdx.x >> 6, lane = threadIdx.x & 63, li = lane & 15, q = lane >> 4;
    int rg = lb & 1, ch = lb >> 1;
    int t0 = ch * 10, t1 = t0 + 10 < NTILES ? t0 + 10 : NTILES;
    if (t0 >= t1) return;
    int r0 = rg * 128 + w * 32;
    short8 a0[16], a1[16];
    const short8* Sp0 = Sprev + (size_t)(r0 + li) * 64 + q;
    const short8* Sp1 = Sprev + (size_t)(r0 + 16 + li) * 64 + q;
#pragma unroll
    for (int kt = 0; kt < 16; kt++) { a0[kt] = Sp0[kt * 4]; a1[kt] = Sp1[kt * 4]; }

    float s0[4] = {0.f,0.f,0.f,0.f}, s1[4] = {0.f,0.f,0.f,0.f};
    stage_tile(Bsw + (size_t)t0 * 1024, lds[0], w, lane);
    int ib = 0;
    for (int ct = t0; ct < t1; ++ct, ib ^= 1) {
        __syncthreads();
        if (ct + 1 < t1) stage_tile(Bsw + (size_t)(ct + 1) * 1024, lds[ib ^ 1], w, lane);
        const short8* B = lds[ib];
        f32x4 c0 = {0.f,0.f,0.f,0.f}, c1 = {0.f,0.f,0.f,0.f};
#pragma unroll
        for (int kt = 0; kt < 16; kt++) {
            short8 bv = B[kt * 64 + lane];
            c0 = MFMA16(a0[kt], bv, c0);
            c1 = MFMA16(a1[kt], bv, c1);
        }
        int col = ct * 16 + li;
        if (col < NV) {
            float obv = ob[col];
#pragma unroll
            for (int r = 0; r < 4; r++) {
                s0[r] += __expf(c0[r] + obv);
                s1[r] += __expf(c1[r] + obv);
            }
        }
    }
#pragma unroll
    for (int off = 1; off < 16; off <<= 1) {
#pragma unroll
        for (int r = 0; r < 4; r++) { s0[r] += __shfl_xor(s0[r], off); s1[r] += __shfl_xor(s1[r], off); }
    }
    if (li == 0) {
#pragma unroll
        for (int r = 0; r < 4; r++) {
            atomicAdd(&sume_t[r0 + q * 4 + r], s0[r]);
            atomicAdd(&sume_t[r0 + 16 + q * 4 + r], s1[r]);
        }
    }
}

// ---------------- per-step launch: blocks<128 recurrence, blocks>=128 lse for t-1 ----------------
__global__ __launch_bounds__(256) void step_t_k(const short8* __restrict__ BHsw,
                                                const __hip_bfloat16* __restrict__ pre_t,
                                                float* __restrict__ c,
                                                const __hip_bfloat16* __restrict__ hc,
                                                __hip_bfloat16* __restrict__ hn,
                                                __hip_bfloat16* __restrict__ St,
                                                const short8* __restrict__ Sprev,
                                                const short8* __restrict__ outSw,
                                                const float* __restrict__ ob,
                                                float* __restrict__ sume_t) {
    __shared__ short8 lds[2][1024];
    int w = threadIdx.x >> 6, lane = threadIdx.x & 63, li = lane & 15, q = lane >> 4;
    if (blockIdx.x < 128) {
        int wid = blockIdx.x * 4 + w;        // 0..511 : 16 mt x 32 jt
        int mt = wid >> 5, jt = wid & 31;
        const short8* Ap = (const short8*)hc + (size_t)(mt * 16 + li) * 64 + q;
        const short8* B0 = BHsw + (size_t)jt * 1024 + lane;
        const short8* B1 = B0 + 32768;
        const short8* B2 = B0 + 65536;
        const short8* B3 = B0 + 98304;
        const short8* B4 = B0 + 131072;

        f32x4 g0 = {0.f,0.f,0.f,0.f}, g1 = g0, g2 = g0, g3 = g0, g4 = g0;
#pragma unroll
        for (int kt = 0; kt < 16; kt++) {
            short8 av = Ap[kt * 4];
            g0 = MFMA16(av, B0[kt * 64], g0);
            g1 = MFMA16(av, B1[kt * 64], g1);
            g2 = MFMA16(av, B2[kt * 64], g2);
            g3 = MFMA16(av, B3[kt * 64], g3);
            g4 = MFMA16(av, B4[kt * 64], g4);
        }
        int jcol = jt * 16 + li;
#pragma unroll
        for (int r = 0; r < 4; r++) {
            int row = mt * 16 + q * 4 + r;
            const __hip_bfloat16* pv = pre_t + (size_t)row * NC;
            float ig = sigf(g0[r] + __bfloat162float(pv[jcol]));
            float fg = sigf(g1[r] + __bfloat162float(pv[512 + jcol]));
            float gg = tanhf(g2[r] + __bfloat162float(pv[1024 + jcol]));
            float og = sigf(g3[r] + __bfloat162float(pv[1536 + jcol]));
            float gp = sigf(g4[r] + __bfloat162float(pv[2048 + jcol]));
            int idx = row * 512 + jcol;
            float cn = fg * c[idx] + ig * gg;
            float tc = tanhf(cn);
            c[idx] = cn;
            hn[idx] = __float2bfloat16(og * tc);
            St[idx] = __float2bfloat16(gp * tc);
        }
    } else {
        if (sume_t == nullptr) return;       // t==0: nothing to reduce yet
        lse_dev(blockIdx.x - 128, Sprev, outSw, ob, sume_t, lds);
    }
}

// tail: lse for t=63
__global__ __launch_bounds__(256) void lse_tail(const short8* __restrict__ Sprev,
                                                const short8* __restrict__ outSw,
                                                const float* __restrict__ ob,
                                                float* __restrict__ sume_t) {
    __shared__ short8 lds[2][1024];
    lse_dev(blockIdx.x, Sprev, outSw, ob, sume_t, lds);
}

// out[row] = mask * (dot(S[row], out_W[:,tgt]) + ob[tgt] - log(sumexp[row]))
__global__ __launch_bounds__(256) void finalize_k(const __hip_bfloat16* __restrict__ S,
                                                  const __hip_bfloat16* __restrict__ Wt,
                                                  const float* __restrict__ ob,
                                                  const int* __restrict__ seqz,
                                                  const float* __restrict__ sumexp,
                                                  float* __restrict__ out) {
    int w = threadIdx.x >> 6, lane = threadIdx.x & 63;
    int row = blockIdx.x * 4 + w;        // 16384 rows, row = t*256 + b
    int t = row >> 8, b = row & 255;
    int tgt = seqz[b * TT + t];
    short8 sv = ((const short8*)(S + (size_t)row * 512))[lane];
    short8 wv = ((const short8*)(Wt + (size_t)tgt * 512))[lane];
    float d = 0.f;
#pragma unroll
    for (int i = 0; i < 8; i++) d += bf2f(sv[i]) * bf2f(wv[i]);
#pragma unroll
    for (int off = 1; off < 64; off <<= 1) d += __shfl_xor(d, off);
    if (lane == 0) {
        bool mk = (t == 0) || (seqz[b * TT + t - 1] != 0);
        out[row] = mk ? (d + ob[tgt] - logf(sumexp[row])) : 0.f;
    }
}

// ---------------- host ----------------

extern "C" void kernel_launch(void* const* d_in, const int* in_sizes, int n_in,
                              void* d_out, int out_size, void* d_ws, size_t ws_size,
                              hipStream_t stream) {
    const float* vis     = (const float*)d_in[0];
    const int*   seqz    = (const int*)d_in[1];
    const float* emb     = (const float*)d_in[2];
    const float* W_ih    = (const float*)d_in[3];
    const float* W_hh    = (const float*)d_in[4];
    const float* b_lstm  = (const float*)d_in[5];
    const float* vis2g_W = (const float*)d_in[6];
    const float* vis2g_b = (const float*)d_in[7];
    const float* w2g_W   = (const float*)d_in[8];
    const float* h2g_W   = (const float*)d_in[9];
    const float* out_W   = (const float*)d_in[10];
    const float* out_b   = (const float*)d_in[11];
    float* out = (float*)d_out;

    char* p = (char*)d_ws;
    auto carve = [&](size_t bytes) {
        void* r = (void*)p;
        p += (bytes + 255) & ~(size_t)255;
        return r;
    };
    __hip_bfloat16* WcatW = (__hip_bfloat16*)carve((size_t)NC * 512 * 2);       // [2560][512]
    __hip_bfloat16* WcatH = (__hip_bfloat16*)carve((size_t)NC * 512 * 2);       // [2560][512]
    __hip_bfloat16* visWt = (__hip_bfloat16*)carve((size_t)NC * 1024 * 2);      // [2560][1024]
    __hip_bfloat16* outWt = (__hip_bfloat16*)carve((size_t)NVP * 512 * 2);      // [10016][512]
    short8*         outSw = (short8*)carve((size_t)NTILES * 16384);             // frag order
    short8*         preBsw= (short8*)carve((size_t)160 * 16384);                // frag order
    short8*         WHsw  = (short8*)carve((size_t)160 * 16384);                // frag order
    __hip_bfloat16* visB  = (__hip_bfloat16*)carve((size_t)256 * 1024 * 2);
    float*          visC  = (float*)carve((size_t)256 * NC * 4);
    __hip_bfloat16* pre   = (__hip_bfloat16*)carve((size_t)TT * 256 * NC * 2);  // 84 MB
    float*          cbuf  = (float*)carve((size_t)256 * 512 * 4);
    __hip_bfloat16* hb0   = (__hip_bfloat16*)carve((size_t)256 * 512 * 2);
    __hip_bfloat16* hb1   = (__hip_bfloat16*)carve((size_t)256 * 512 * 2);
    __hip_bfloat16* S     = (__hip_bfloat16*)carve((size_t)TT * 256 * 512 * 2);
    float*          sume  = (float*)carve((size_t)TT * 256 * 4);

    // prep: 1 transpose launch (10128 tiles), 1 swizzle launch, 1 init launch
    prep_tr<<<10128, dim3(32, 8), 0, stream>>>(W_ih, W_hh, w2g_W, h2g_W, vis2g_W, out_W,
                                               WcatW, WcatH, visWt, outWt);
    swz_all<<<3784, 256, 0, stream>>>((const short8*)outWt, (const short8*)WcatW,
                                      (const short8*)WcatH, outSw, preBsw, WHsw);
    init_misc<<<1536, 256, 0, stream>>>(cbuf, hb0, vis, visB);

    gemm_vis<<<640, 256, 0, stream>>>(visB, visWt, b_lstm, vis2g_b, visC);
    pre_gemm<<<dim3(128, 8), 256, 0, stream>>>(seqz, emb, preBsw, visC, pre);

    hipMemsetAsync(sume, 0, (size_t)TT * 256 * 4, stream);

    __hip_bfloat16* hcur = hb0;
    __hip_bfloat16* hnxt = hb1;
    for (int t = 0; t < TT; ++t) {
        int tp = (t > 0) ? t - 1 : 0;
        step_t_k<<<256, 256, 0, stream>>>(WHsw, pre + (size_t)t * 256 * NC, cbuf,
                                          hcur, hnxt, S + (size_t)t * 131072,
                                          (const short8*)(S + (size_t)tp * 131072),
                                          outSw, out_b,
                                          (t > 0) ? (sume + (size_t)(t - 1) * 256) : (float*)nullptr);
        __hip_bfloat16* tmp = hcur; hcur = hnxt; hnxt = tmp;
    }
    lse_tail<<<128, 256, 0, stream>>>((const short8*)(S + (size_t)63 * 131072), outSw,
                                      out_b, sume + (size_t)63 * 256);
    finalize_k<<<4096, 256, 0, stream>>>(S, outWt, out_b, seqz, sume, out);
}